// Round 1
// baseline (33542.740 us; speedup 1.0000x reference)
//
#include <hip/hip_runtime.h>
#include <hip/hip_fp16.h>

// Problem constants
#define S_LEN 2048
#define B_DIM 64
#define H_DIM 512
#define G2    1024                  // packed (z,n) gate columns
#define SBH   (S_LEN * B_DIM * H_DIM)   // 67108864

// Workspace layout (bytes). Total ~4.46 MB.
#define WS_CTR    0
#define WS_BIAS   256
#define WS_WIH_HI (8192)
#define WS_WIH_LO (8192 + 1 * 1048576)
#define WS_WHH_HI (8192 + 2 * 1048576)
#define WS_WHH_LO (8192 + 3 * 1048576)
#define WS_HPP    (8192 + 4 * 1048576)   // 2 ping-pong buffers, stride 131072 (hi 64KB + lo 64KB)

typedef __attribute__((ext_vector_type(8))) short short8;
typedef __attribute__((ext_vector_type(4))) float floatx4;
typedef __attribute__((ext_vector_type(4))) unsigned short ushort4_t;

__device__ __forceinline__ unsigned short f2b(float f) {   // fp32 -> bf16 RNE
  unsigned u = __float_as_uint(f);
  u = u + 0x7FFFu + ((u >> 16) & 1u);
  return (unsigned short)(u >> 16);
}
__device__ __forceinline__ float b2f(unsigned short h) {
  return __uint_as_float(((unsigned)h) << 16);
}

// async global->LDS, 16B per lane; LDS dest = base + lane*16 (wave-uniform base)
__device__ __forceinline__ void async16(const void* g, void* l) {
  __builtin_amdgcn_global_load_lds(
      (const __attribute__((address_space(1))) unsigned int*)g,
      (__attribute__((address_space(3))) unsigned int*)l, 16, 0, 0);
}

// ---------------------------------------------------------------------------
// Prep: pack W_ih / W_hh (rows H..3H, (z,n)-interleaved cols) into bf16 hi/lo,
// combined bias, h0 hi/lo into ping buffer 0, zero barrier counter.
// Grid: 2048 x 256  (one thread per (p,k) of 1024x512)
// ---------------------------------------------------------------------------
__global__ __launch_bounds__(256) void prep_kernel(
    const float* __restrict__ h0, const float* __restrict__ wih,
    const float* __restrict__ whh, const float* __restrict__ bih,
    const float* __restrict__ bhh, char* __restrict__ ws) {
  int gid = blockIdx.x * 256 + threadIdx.x;       // 0..524287
  int p = gid >> 9, k = gid & 511;
  // packed col p: even -> z row (H + c), odd -> n row (2H + c), c = p>>1
  int src = (p & 1) ? (2 * H_DIM + (p >> 1)) : (H_DIM + (p >> 1));
  float wi = wih[src * 512 + k];
  float wh = whh[src * 512 + k];
  unsigned short wi_hi = f2b(wi);
  unsigned short wi_lo = f2b(wi - b2f(wi_hi));
  unsigned short wh_hi = f2b(wh);
  unsigned short wh_lo = f2b(wh - b2f(wh_hi));
  int off = p * 512 + k;
  ((unsigned short*)(ws + WS_WIH_HI))[off] = wi_hi;
  ((unsigned short*)(ws + WS_WIH_LO))[off] = wi_lo;
  ((unsigned short*)(ws + WS_WHH_HI))[off] = wh_hi;
  ((unsigned short*)(ws + WS_WHH_LO))[off] = wh_lo;
  if (gid < B_DIM * H_DIM) {                       // h0 -> ping buffer 0
    float h = h0[gid];
    unsigned short hi = f2b(h);
    unsigned short lo = f2b(h - b2f(hi));
    ((unsigned short*)(ws + WS_HPP))[gid] = hi;
    ((unsigned short*)(ws + WS_HPP + 65536))[gid] = lo;
  }
  if (gid < G2) {
    int sr = (gid & 1) ? (2 * H_DIM + (gid >> 1)) : (H_DIM + (gid >> 1));
    ((float*)(ws + WS_BIAS))[gid] = bih[sr] + bhh[sr];
  }
  if (gid == 0) *((unsigned*)(ws + WS_CTR)) = 0u;
}

// ---------------------------------------------------------------------------
// gx GEMM: G[R][p] = sum_k x[R][k] * Wp[p][k] + bias[p], R = s*64+b.
// 3-term bf16 hi/lo split (~fp32 accurate). Output: fp16 (z,n) pairs stored
// at the dword of ys[s][b][c] in d_out (same byte address, c = p>>1).
// Tiles: BM=128, BN=128, BK=32. Grid: (8, 1024), 256 threads.
// ---------------------------------------------------------------------------
#define AHI 0
#define ALO 10240
#define BHI 20480
#define BLO 30720

__global__ __launch_bounds__(256, 1) void gxk_kernel(
    const float* __restrict__ x, const char* __restrict__ ws,
    float* __restrict__ out) {
  __shared__ char lds[40960];   // rows padded to 80B (2-way bank alias = free)
  int tid = threadIdx.x;
  int lane = tid & 63, w = tid >> 6;
  int q = lane >> 4, m16 = lane & 15;
  int by = blockIdx.x;          // N block 0..7
  int bx = blockIdx.y;          // M block 0..1023
  int row0 = bx * 128;
  int col0 = by * 128;
  const unsigned short* whi = (const unsigned short*)(ws + WS_WIH_HI);
  const unsigned short* wlo = (const unsigned short*)(ws + WS_WIH_LO);

  floatx4 acc[8][2];
#pragma unroll
  for (int i = 0; i < 8; i++)
#pragma unroll
    for (int j = 0; j < 2; j++) acc[i][j] = (floatx4){0.f, 0.f, 0.f, 0.f};

  int arow[4], akq[4], brow[2], bkc[2];
#pragma unroll
  for (int i = 0; i < 4; i++) { int c = tid + 256 * i; arow[i] = c >> 3; akq[i] = c & 7; }
#pragma unroll
  for (int i = 0; i < 2; i++) { int c = tid + 256 * i; brow[i] = c >> 2; bkc[i] = c & 3; }

  float4 xa[4];
  uint4 wbh[2], wbl[2];
#pragma unroll
  for (int i = 0; i < 4; i++)
    xa[i] = *(const float4*)(x + (long)(row0 + arow[i]) * 512 + akq[i] * 4);
#pragma unroll
  for (int i = 0; i < 2; i++) {
    wbh[i] = *(const uint4*)(whi + (col0 + brow[i]) * 512 + bkc[i] * 8);
    wbl[i] = *(const uint4*)(wlo + (col0 + brow[i]) * 512 + bkc[i] * 8);
  }

  for (int kk = 0; kk < 16; ++kk) {
    __syncthreads();   // previous iter's frag reads done before overwrite
#pragma unroll
    for (int i = 0; i < 4; i++) {
      float v[4] = {xa[i].x, xa[i].y, xa[i].z, xa[i].w};
      ushort4_t hi4, lo4;
#pragma unroll
      for (int e = 0; e < 4; e++) {
        unsigned short h = f2b(v[e]);
        hi4[e] = h;
        lo4[e] = f2b(v[e] - b2f(h));
      }
      *(ushort4_t*)(lds + AHI + arow[i] * 80 + akq[i] * 8) = hi4;
      *(ushort4_t*)(lds + ALO + arow[i] * 80 + akq[i] * 8) = lo4;
    }
#pragma unroll
    for (int i = 0; i < 2; i++) {
      *(uint4*)(lds + BHI + brow[i] * 80 + bkc[i] * 16) = wbh[i];
      *(uint4*)(lds + BLO + brow[i] * 80 + bkc[i] * 16) = wbl[i];
    }
    __syncthreads();
    if (kk < 15) {   // prefetch next K-slab into regs; latency hides under MFMA
      int k0 = (kk + 1) * 32;
#pragma unroll
      for (int i = 0; i < 4; i++)
        xa[i] = *(const float4*)(x + (long)(row0 + arow[i]) * 512 + k0 + akq[i] * 4);
#pragma unroll
      for (int i = 0; i < 2; i++) {
        wbh[i] = *(const uint4*)(whi + (col0 + brow[i]) * 512 + k0 + bkc[i] * 8);
        wbl[i] = *(const uint4*)(wlo + (col0 + brow[i]) * 512 + k0 + bkc[i] * 8);
      }
    }
    short8 bh[2], bl[2];
#pragma unroll
    for (int j = 0; j < 2; j++) {
      bh[j] = *(short8*)(lds + BHI + (w * 32 + j * 16 + m16) * 80 + q * 16);
      bl[j] = *(short8*)(lds + BLO + (w * 32 + j * 16 + m16) * 80 + q * 16);
    }
#pragma unroll
    for (int i = 0; i < 8; i++) {
      short8 ah = *(short8*)(lds + AHI + (i * 16 + m16) * 80 + q * 16);
      short8 al = *(short8*)(lds + ALO + (i * 16 + m16) * 80 + q * 16);
#pragma unroll
      for (int j = 0; j < 2; j++) {
        acc[i][j] = __builtin_amdgcn_mfma_f32_16x16x32_bf16(ah, bh[j], acc[i][j], 0, 0, 0);
        acc[i][j] = __builtin_amdgcn_mfma_f32_16x16x32_bf16(ah, bl[j], acc[i][j], 0, 0, 0);
        acc[i][j] = __builtin_amdgcn_mfma_f32_16x16x32_bf16(al, bh[j], acc[i][j], 0, 0, 0);
      }
    }
  }

  // Epilogue: D col parity == lane parity (bases all even). Pair (z,n) via
  // shfl_xor(1); both lanes build identical pair dword; even lane stores
  // N-tile 0, odd lane stores N-tile 1 -> full-width stores.
  const float* bias = (const float*)(ws + WS_BIAS);
  float bj0 = bias[col0 + w * 32 + m16];
  float bj1 = bias[col0 + w * 32 + 16 + m16];
  int js = lane & 1;
  int pi = m16 >> 1;
  int cb = (col0 >> 1) + w * 16 + js * 8 + pi;
#pragma unroll
  for (int i = 0; i < 8; i++) {
    __half2 sv[4];
#pragma unroll
    for (int j = 0; j < 2; j++) {
#pragma unroll
      for (int r = 0; r < 4; r++) {
        float own = acc[i][j][r] + (j ? bj1 : bj0);
        float other = __shfl_xor(own, 1, 64);
        float zv = js ? other : own;
        float nv = js ? own : other;
        __half2 hp = __halves2half2(__float2half(zv), __float2half(nv));
        if (j == js) sv[r] = hp;
      }
    }
#pragma unroll
    for (int r = 0; r < 4; r++) {
      long R = row0 + i * 16 + q * 4 + r;
      *(__half2*)(out + R * 512 + cb) = sv[r];
    }
  }
}

// ---------------------------------------------------------------------------
// Persistent scan: 64 blocks = 4 batch-groups x 16 col-chunks, 256 threads.
// Each wave holds its W_hh slice (16 packed cols x K=512, hi+lo) in 128 VGPRs
// for all 2048 steps. h ping-pongs through ws (hi/lo bf16); h value itself is
// carried in registers per lane. Grid barrier: monotonic counter, agent scope.
// ---------------------------------------------------------------------------
__global__ __launch_bounds__(256, 1) void scan_kernel(
    const float* __restrict__ h0, char* __restrict__ ws,
    float* __restrict__ out) {
  __shared__ char lds[33280];   // 32 rows (16 hi + 16 lo) x 1040B (pad 16)
  int tid = threadIdx.x;
  int lane = tid & 63, w = tid >> 6;
  int q = lane >> 4, n16 = lane & 15;
  int bid = blockIdx.x;
  int bg = bid >> 4, cc = bid & 15;
  int b0 = bg * 16;
  int pw = cc * 64 + w * 16;    // wave's packed-col base
  const unsigned short* whh_hi = (const unsigned short*)(ws + WS_WHH_HI);
  const unsigned short* whh_lo = (const unsigned short*)(ws + WS_WHH_LO);
  unsigned* ctr = (unsigned*)(ws + WS_CTR);

  short8 Bh[16], Bl[16];        // resident weights: 128 VGPRs
#pragma unroll
  for (int kk = 0; kk < 16; kk++) {
    Bh[kk] = *(const short8*)(whh_hi + (pw + n16) * 512 + kk * 32 + q * 8);
    Bl[kk] = *(const short8*)(whh_lo + (pw + n16) * 512 + kk * 32 + q * 8);
  }

  int c = cc * 32 + w * 8 + (n16 >> 1);   // my h column
  int bq = b0 + q * 4;                    // my batch base (rows r=0..3)
  int odd = lane & 1;
  float h[4];
#pragma unroll
  for (int r = 0; r < 4; r++) h[r] = h0[(bq + r) * 512 + c];

  char* hpp = ws + WS_HPP;

#pragma unroll 1
  for (int t = 0; t < S_LEN; ++t) {
    // G prefetch: fp16 (z,n) pair lives at the dword of ys[t][b][c]
    unsigned gw[4];
#pragma unroll
    for (int r = 0; r < 4; r++)
      gw[r] = *(const unsigned*)(out + (long)(t * 64 + bq + r) * 512 + c);

    // stage h (my 16 batches, hi+lo) global -> LDS
    const char* hcur = hpp + (t & 1) * 131072;
#pragma unroll
    for (int i = 0; i < 8; i++) {
      int row = w * 8 + i;   // 0..15 hi, 16..31 lo
      const char* g = hcur +
          ((row < 16) ? ((b0 + row) * 1024) : (65536 + (b0 + row - 16) * 1024)) +
          lane * 16;
      async16(g, lds + row * 1040);
    }
    __syncthreads();   // implies vmcnt(0): staged data ready

    floatx4 acc = {0.f, 0.f, 0.f, 0.f};
#pragma unroll
    for (int kk = 0; kk < 16; kk++) {
      short8 ah = *(short8*)(lds + n16 * 1040 + kk * 64 + q * 16);
      short8 al = *(short8*)(lds + 16640 + n16 * 1040 + kk * 64 + q * 16);
      acc = __builtin_amdgcn_mfma_f32_16x16x32_bf16(ah, Bh[kk], acc, 0, 0, 0);
      acc = __builtin_amdgcn_mfma_f32_16x16x32_bf16(ah, Bl[kk], acc, 0, 0, 0);
      acc = __builtin_amdgcn_mfma_f32_16x16x32_bf16(al, Bh[kk], acc, 0, 0, 0);
    }

    // epilogue: pair z/n across adjacent lanes, update h
    char* hnext = hpp + ((t & 1) ^ 1) * 131072;
#pragma unroll
    for (int r = 0; r < 4; r++) {
      __half2 gp = *(__half2*)&gw[r];
      float gz = __low2float(gp), gn = __high2float(gp);
      float own = acc[r] + (odd ? gn : gz);
      float other = __shfl_xor(own, 1, 64);
      float zpre = odd ? other : own;
      float npre = odd ? own : other;
      float zv = 1.f / (1.f + __expf(-zpre));
      float nv = tanhf(npre);
      h[r] = (1.f - zv) * h[r] + zv * nv;
    }
    if (!odd) {   // even lanes: fp32 output (overwrites my G dwords)
#pragma unroll
      for (int r = 0; r < 4; r++)
        out[(long)(t * 64 + bq + r) * 512 + c] = h[r];
      if (t == S_LEN - 1) {
#pragma unroll
        for (int r = 0; r < 4; r++)
          out[(long)SBH + (bq + r) * 512 + c] = h[r];
      }
    } else {      // odd lanes: publish bf16 hi/lo for next step
#pragma unroll
      for (int r = 0; r < 4; r++) {
        unsigned short hi = f2b(h[r]);
        unsigned short lo = f2b(h[r] - b2f(hi));
        *(unsigned short*)(hnext + (bq + r) * 1024 + c * 2) = hi;
        *(unsigned short*)(hnext + 65536 + (bq + r) * 1024 + c * 2) = lo;
      }
    }

    // grid barrier (monotonic counter; safe: first passer of step t requires
    // all 64 arrivals since laggards cap the sum below 64*(t+1))
    __threadfence();
    __syncthreads();
    if (tid == 0) {
      __hip_atomic_fetch_add(ctr, 1u, __ATOMIC_ACQ_REL, __HIP_MEMORY_SCOPE_AGENT);
      unsigned target = 64u * (unsigned)(t + 1);
      while (__hip_atomic_load(ctr, __ATOMIC_ACQUIRE, __HIP_MEMORY_SCOPE_AGENT) < target)
        __builtin_amdgcn_s_sleep(2);
    }
    __syncthreads();
    __threadfence();
  }
}

// ---------------------------------------------------------------------------
extern "C" void kernel_launch(void* const* d_in, const int* in_sizes, int n_in,
                              void* d_out, int out_size, void* d_ws, size_t ws_size,
                              hipStream_t stream) {
  const float* x   = (const float*)d_in[0];
  const float* h0  = (const float*)d_in[1];
  const float* wih = (const float*)d_in[2];
  const float* whh = (const float*)d_in[3];
  const float* bih = (const float*)d_in[4];
  const float* bhh = (const float*)d_in[5];
  float* out = (float*)d_out;
  char* ws = (char*)d_ws;

  prep_kernel<<<2048, 256, 0, stream>>>(h0, wih, whh, bih, bhh, ws);
  gxk_kernel<<<dim3(8, 1024), 256, 0, stream>>>(x, ws, out);

  const float* h0p = h0;
  char* wsp = ws;
  float* outp = out;
  void* kargs[] = {(void*)&h0p, (void*)&wsp, (void*)&outp};
  hipLaunchCooperativeKernel(scan_kernel, dim3(64), dim3(256), kargs, 0, stream);
}

// Round 2
// 10090.825 us; speedup vs baseline: 3.3241x; 3.3241x over previous
//
#include <hip/hip_runtime.h>
#include <hip/hip_fp16.h>
#include <stdint.h>

// Problem constants
#define S_LEN 2048
#define B_DIM 64
#define H_DIM 512
#define G2    1024                  // packed (z,n) gate columns
#define SBH   (S_LEN * B_DIM * H_DIM)   // 67108864

// Workspace layout (bytes).
#define WS_FLAGS  0                  // 64 flags, 64 B apart (4 KB)
#define WS_BIAS   4096               // 1024 floats (4 KB)
#define WS_WIH_HI (8192)
#define WS_WIH_LO (8192 + 1 * 1048576)
#define WS_WHH_HI (8192 + 2 * 1048576)
#define WS_WHH_LO (8192 + 3 * 1048576)
#define WS_HPP    (8192 + 4 * 1048576)   // 2 ping-pong h buffers, stride 131072
// h buffer layout: hi-plane 64 KB (batch b at b*1024, cols XOR-swizzled) + lo-plane 64 KB.
// Swizzle: value (b,c) lives at plane + b*1024 + (( (c>>3) ^ (b&7) ))*16 + (c&7)*2.

typedef __attribute__((ext_vector_type(8))) short short8;
typedef __attribute__((ext_vector_type(4))) float floatx4;
typedef __attribute__((ext_vector_type(4))) unsigned short ushort4_t;
typedef __attribute__((ext_vector_type(4))) unsigned int uint4v;

__device__ __forceinline__ unsigned short f2b(float f) {   // fp32 -> bf16 RNE
  unsigned u = __float_as_uint(f);
  u = u + 0x7FFFu + ((u >> 16) & 1u);
  return (unsigned short)(u >> 16);
}
__device__ __forceinline__ float b2f(unsigned short h) {
  return __uint_as_float(((unsigned)h) << 16);
}

// ---------------------------------------------------------------------------
// Prep: pack W_ih / W_hh (z,n rows, packed cols) into bf16 hi/lo, combined
// bias, h0 (swizzled hi/lo) into ping buffer 0, zero the barrier flags.
// ---------------------------------------------------------------------------
__global__ __launch_bounds__(256) void prep_kernel(
    const float* __restrict__ h0, const float* __restrict__ wih,
    const float* __restrict__ whh, const float* __restrict__ bih,
    const float* __restrict__ bhh, char* __restrict__ ws) {
  int gid = blockIdx.x * 256 + threadIdx.x;       // 0..524287
  int p = gid >> 9, k = gid & 511;
  int src = (p & 1) ? (2 * H_DIM + (p >> 1)) : (H_DIM + (p >> 1));
  float wi = wih[src * 512 + k];
  float wh = whh[src * 512 + k];
  unsigned short wi_hi = f2b(wi);
  unsigned short wi_lo = f2b(wi - b2f(wi_hi));
  unsigned short wh_hi = f2b(wh);
  unsigned short wh_lo = f2b(wh - b2f(wh_hi));
  int off = p * 512 + k;
  ((unsigned short*)(ws + WS_WIH_HI))[off] = wi_hi;
  ((unsigned short*)(ws + WS_WIH_LO))[off] = wi_lo;
  ((unsigned short*)(ws + WS_WHH_HI))[off] = wh_hi;
  ((unsigned short*)(ws + WS_WHH_LO))[off] = wh_lo;
  if (gid < B_DIM * H_DIM) {                       // h0 -> ping buffer 0 (swizzled)
    int b = gid >> 9, c = gid & 511;
    float h = h0[gid];
    unsigned short hi = f2b(h);
    unsigned short lo = f2b(h - b2f(hi));
    int g = (c >> 3) ^ (b & 7);
    int byteoff = b * 1024 + g * 16 + (c & 7) * 2;
    *(unsigned short*)(ws + WS_HPP + byteoff) = hi;
    *(unsigned short*)(ws + WS_HPP + 65536 + byteoff) = lo;
  }
  if (gid < G2) {
    int sr = (gid & 1) ? (2 * H_DIM + (gid >> 1)) : (H_DIM + (gid >> 1));
    ((float*)(ws + WS_BIAS))[gid] = bih[sr] + bhh[sr];
  }
  if (gid < 64) ((unsigned*)(ws + WS_FLAGS))[gid * 16] = 0u;
}

// ---------------------------------------------------------------------------
// gx GEMM (unchanged from round 1): G[R][p] fp16 (z,n) pairs into d_out.
// ---------------------------------------------------------------------------
#define AHI 0
#define ALO 10240
#define BHI 20480
#define BLO 30720

__global__ __launch_bounds__(256, 1) void gxk_kernel(
    const float* __restrict__ x, const char* __restrict__ ws,
    float* __restrict__ out) {
  __shared__ char lds[40960];
  int tid = threadIdx.x;
  int lane = tid & 63, w = tid >> 6;
  int q = lane >> 4, m16 = lane & 15;
  int by = blockIdx.x;
  int bx = blockIdx.y;
  int row0 = bx * 128;
  int col0 = by * 128;
  const unsigned short* whi = (const unsigned short*)(ws + WS_WIH_HI);
  const unsigned short* wlo = (const unsigned short*)(ws + WS_WIH_LO);

  floatx4 acc[8][2];
#pragma unroll
  for (int i = 0; i < 8; i++)
#pragma unroll
    for (int j = 0; j < 2; j++) acc[i][j] = (floatx4){0.f, 0.f, 0.f, 0.f};

  int arow[4], akq[4], brow[2], bkc[2];
#pragma unroll
  for (int i = 0; i < 4; i++) { int c = tid + 256 * i; arow[i] = c >> 3; akq[i] = c & 7; }
#pragma unroll
  for (int i = 0; i < 2; i++) { int c = tid + 256 * i; brow[i] = c >> 2; bkc[i] = c & 3; }

  float4 xa[4];
  uint4 wbh[2], wbl[2];
#pragma unroll
  for (int i = 0; i < 4; i++)
    xa[i] = *(const float4*)(x + (long)(row0 + arow[i]) * 512 + akq[i] * 4);
#pragma unroll
  for (int i = 0; i < 2; i++) {
    wbh[i] = *(const uint4*)(whi + (col0 + brow[i]) * 512 + bkc[i] * 8);
    wbl[i] = *(const uint4*)(wlo + (col0 + brow[i]) * 512 + bkc[i] * 8);
  }

  for (int kk = 0; kk < 16; ++kk) {
    __syncthreads();
#pragma unroll
    for (int i = 0; i < 4; i++) {
      float v[4] = {xa[i].x, xa[i].y, xa[i].z, xa[i].w};
      ushort4_t hi4, lo4;
#pragma unroll
      for (int e = 0; e < 4; e++) {
        unsigned short h = f2b(v[e]);
        hi4[e] = h;
        lo4[e] = f2b(v[e] - b2f(h));
      }
      *(ushort4_t*)(lds + AHI + arow[i] * 80 + akq[i] * 8) = hi4;
      *(ushort4_t*)(lds + ALO + arow[i] * 80 + akq[i] * 8) = lo4;
    }
#pragma unroll
    for (int i = 0; i < 2; i++) {
      *(uint4*)(lds + BHI + brow[i] * 80 + bkc[i] * 16) = wbh[i];
      *(uint4*)(lds + BLO + brow[i] * 80 + bkc[i] * 16) = wbl[i];
    }
    __syncthreads();
    if (kk < 15) {
      int k0 = (kk + 1) * 32;
#pragma unroll
      for (int i = 0; i < 4; i++)
        xa[i] = *(const float4*)(x + (long)(row0 + arow[i]) * 512 + k0 + akq[i] * 4);
#pragma unroll
      for (int i = 0; i < 2; i++) {
        wbh[i] = *(const uint4*)(whi + (col0 + brow[i]) * 512 + k0 + bkc[i] * 8);
        wbl[i] = *(const uint4*)(wlo + (col0 + brow[i]) * 512 + k0 + bkc[i] * 8);
      }
    }
    short8 bh[2], bl[2];
#pragma unroll
    for (int j = 0; j < 2; j++) {
      bh[j] = *(short8*)(lds + BHI + (w * 32 + j * 16 + m16) * 80 + q * 16);
      bl[j] = *(short8*)(lds + BLO + (w * 32 + j * 16 + m16) * 80 + q * 16);
    }
#pragma unroll
    for (int i = 0; i < 8; i++) {
      short8 ah = *(short8*)(lds + AHI + (i * 16 + m16) * 80 + q * 16);
      short8 al = *(short8*)(lds + ALO + (i * 16 + m16) * 80 + q * 16);
#pragma unroll
      for (int j = 0; j < 2; j++) {
        acc[i][j] = __builtin_amdgcn_mfma_f32_16x16x32_bf16(ah, bh[j], acc[i][j], 0, 0, 0);
        acc[i][j] = __builtin_amdgcn_mfma_f32_16x16x32_bf16(ah, bl[j], acc[i][j], 0, 0, 0);
        acc[i][j] = __builtin_amdgcn_mfma_f32_16x16x32_bf16(al, bh[j], acc[i][j], 0, 0, 0);
      }
    }
  }

  const float* bias = (const float*)(ws + WS_BIAS);
  float bj0 = bias[col0 + w * 32 + m16];
  float bj1 = bias[col0 + w * 32 + 16 + m16];
  int js = lane & 1;
  int pi = m16 >> 1;
  int cb = (col0 >> 1) + w * 16 + js * 8 + pi;
#pragma unroll
  for (int i = 0; i < 8; i++) {
    __half2 sv[4];
#pragma unroll
    for (int j = 0; j < 2; j++) {
#pragma unroll
      for (int r = 0; r < 4; r++) {
        float own = acc[i][j][r] + (j ? bj1 : bj0);
        float other = __shfl_xor(own, 1, 64);
        float zv = js ? other : own;
        float nv = js ? own : other;
        __half2 hp = __halves2half2(__float2half(zv), __float2half(nv));
        if (j == js) sv[r] = hp;
      }
    }
#pragma unroll
    for (int r = 0; r < 4; r++) {
      long R = row0 + i * 16 + q * 4 + r;
      *(__half2*)(out + R * 512 + cb) = sv[r];
    }
  }
}

// ---------------------------------------------------------------------------
// Persistent scan, fence-free. 64 blocks = 4 batch-groups x 16 col-chunks.
// h exchange through device-coherent (sc0 sc1) accesses only; ys/G traffic
// stays normally cached. Barrier = per-block flag slots, relaxed atomics.
// ---------------------------------------------------------------------------
__global__ __launch_bounds__(256, 1) void scan_kernel(
    const float* __restrict__ h0, char* __restrict__ ws,
    float* __restrict__ out) {
  __shared__ char lds[32768];   // hi plane 16 KB + lo plane 16 KB, swizzled image
  int tid = threadIdx.x;
  int lane = tid & 63, w = tid >> 6;
  int q = lane >> 4, n16 = lane & 15;
  int bid = blockIdx.x;
  int bg = bid >> 4, cc = bid & 15;
  int b0 = bg * 16;
  int pw = cc * 64 + w * 16;
  const unsigned short* whh_hi = (const unsigned short*)(ws + WS_WHH_HI);
  const unsigned short* whh_lo = (const unsigned short*)(ws + WS_WHH_LO);
  unsigned* flags = (unsigned*)(ws + WS_FLAGS);

  short8 Bh[16], Bl[16];        // resident weights: 128 VGPRs
#pragma unroll
  for (int kk = 0; kk < 16; kk++) {
    Bh[kk] = *(const short8*)(whh_hi + (pw + n16) * 512 + kk * 32 + q * 8);
    Bl[kk] = *(const short8*)(whh_lo + (pw + n16) * 512 + kk * 32 + q * 8);
  }

  int c = cc * 32 + w * 8 + (n16 >> 1);   // my h column
  int bq = b0 + q * 4;                    // my batch base
  int odd = lane & 1;
  int role = n16 & 3;
  float h[4];
#pragma unroll
  for (int r = 0; r < 4; r++) h[r] = h0[(bq + r) * 512 + c];

  char* hpp = ws + WS_HPP;

#pragma unroll 1
  for (int t = 0; t < S_LEN; ++t) {
    const char* hcur = hpp + (t & 1) * 131072;
    char* hnext = hpp + ((t & 1) ^ 1) * 131072;

    // ---- stage h: device-coherent dwordx4 loads -> regs -> LDS (swizzled) ----
    uint4v hv[8];
#pragma unroll
    for (int i = 0; i < 8; i++) {
      int gidx = tid + 256 * i;            // 16B granule 0..2047
      int plane = gidx >> 10;              // 0=hi, 1=lo
      int row = (gidx >> 6) & 15;
      int off = gidx & 63;
      uint64_t ga = (uint64_t)(uintptr_t)(hcur + plane * 65536 + (b0 + row) * 1024 + off * 16);
      asm volatile("global_load_dwordx4 %0, %1, off sc0 sc1"
                   : "=v"(hv[i]) : "v"(ga));
    }
    asm volatile("s_waitcnt vmcnt(0)" ::: "memory");
#pragma unroll
    for (int i = 0; i < 8; i++) {
      int gidx = tid + 256 * i;
      *(uint4v*)(lds + gidx * 16) = hv[i];
    }
    __syncthreads();

    // ---- G prefetch (cached; completes under MFMA) ----
    unsigned gw[4];
#pragma unroll
    for (int r = 0; r < 4; r++)
      gw[r] = *(const unsigned*)(out + (long)(t * 64 + bq + r) * 512 + c);

    // ---- MFMA: gates += h @ Whh^T (3-term bf16 split) ----
    floatx4 acc = {0.f, 0.f, 0.f, 0.f};
#pragma unroll
    for (int kk = 0; kk < 16; kk++) {
      int gs = (kk * 4 + q) ^ (n16 & 7);
      short8 ah = *(short8*)(lds + n16 * 1024 + gs * 16);
      short8 al = *(short8*)(lds + 16384 + n16 * 1024 + gs * 16);
      acc = __builtin_amdgcn_mfma_f32_16x16x32_bf16(ah, Bh[kk], acc, 0, 0, 0);
      acc = __builtin_amdgcn_mfma_f32_16x16x32_bf16(ah, Bl[kk], acc, 0, 0, 0);
      acc = __builtin_amdgcn_mfma_f32_16x16x32_bf16(al, Bh[kk], acc, 0, 0, 0);
    }

    // ---- epilogue: gate pair via shfl, h update ----
#pragma unroll
    for (int r = 0; r < 4; r++) {
      __half2 gp = *(__half2*)&gw[r];
      float own = acc[r] + (odd ? __high2float(gp) : __low2float(gp));
      float other = __shfl_xor(own, 1, 64);
      float zpre = odd ? other : own;
      float npre = odd ? own : other;
      float zv = 1.f / (1.f + __expf(-zpre));
      float nv = tanhf(npre);
      h[r] = (1.f - zv) * h[r] + zv * nv;
    }
    float hp[4];   // column-pair partner's h (cross-lane op: all lanes execute)
#pragma unroll
    for (int r = 0; r < 4; r++) hp[r] = __shfl_xor(h[r], 2, 64);

    // ---- publish h (UC) + ys (cached) by lane role ----
    if (role == 0) {          // col even: hi-plane dword {hi(c), hi(c+1)}
#pragma unroll
      for (int r = 0; r < 4; r++) {
        int b = bq + r;
        int g = (c >> 3) ^ (b & 7);
        unsigned dw = (unsigned)f2b(h[r]) | ((unsigned)f2b(hp[r]) << 16);
        __hip_atomic_store((unsigned*)(hnext + b * 1024 + g * 16 + (c & 7) * 2),
                           dw, __ATOMIC_RELAXED, __HIP_MEMORY_SCOPE_AGENT);
      }
    } else if (role == 1) {   // col even: lo-plane dword
#pragma unroll
      for (int r = 0; r < 4; r++) {
        int b = bq + r;
        int g = (c >> 3) ^ (b & 7);
        unsigned short mlo = f2b(h[r] - b2f(f2b(h[r])));
        unsigned short plo = f2b(hp[r] - b2f(f2b(hp[r])));
        unsigned dw = (unsigned)mlo | ((unsigned)plo << 16);
        __hip_atomic_store((unsigned*)(hnext + 65536 + b * 1024 + g * 16 + (c & 7) * 2),
                           dw, __ATOMIC_RELAXED, __HIP_MEMORY_SCOPE_AGENT);
      }
    } else if (role == 2) {   // col odd: ys float2 {h(c-1), h(c)} (cached)
#pragma unroll
      for (int r = 0; r < 4; r++) {
        long R = t * 64 + bq + r;
        *(float2*)(out + R * 512 + (c - 1)) = make_float2(hp[r], h[r]);
      }
    } else if (t == S_LEN - 1) {  // role 3: final h_n
#pragma unroll
      for (int r = 0; r < 4; r++)
        *(float2*)(out + (long)SBH + (bq + r) * 512 + (c - 1)) = make_float2(hp[r], h[r]);
    }

    // ---- fence-free barrier: drain stores, set flag, poll 64 flags ----
    __threadfence_block();     // s_waitcnt only; no cache maintenance
    __syncthreads();           // compiler drains vmcnt(0) before s_barrier
    if (tid == 0)
      __hip_atomic_store(&flags[bid * 16], (unsigned)(t + 1),
                         __ATOMIC_RELAXED, __HIP_MEMORY_SCOPE_AGENT);
    if (w == 0) {
      unsigned v;
      do {
        v = __hip_atomic_load(&flags[lane * 16], __ATOMIC_RELAXED,
                              __HIP_MEMORY_SCOPE_AGENT);
      } while (!__all(v > (unsigned)t));
    }
    __syncthreads();
  }
}

// ---------------------------------------------------------------------------
extern "C" void kernel_launch(void* const* d_in, const int* in_sizes, int n_in,
                              void* d_out, int out_size, void* d_ws, size_t ws_size,
                              hipStream_t stream) {
  const float* x   = (const float*)d_in[0];
  const float* h0  = (const float*)d_in[1];
  const float* wih = (const float*)d_in[2];
  const float* whh = (const float*)d_in[3];
  const float* bih = (const float*)d_in[4];
  const float* bhh = (const float*)d_in[5];
  float* out = (float*)d_out;
  char* ws = (char*)d_ws;

  prep_kernel<<<2048, 256, 0, stream>>>(h0, wih, whh, bih, bhh, ws);
  gxk_kernel<<<dim3(8, 1024), 256, 0, stream>>>(x, ws, out);

  const float* h0p = h0;
  char* wsp = ws;
  float* outp = out;
  void* kargs[] = {(void*)&h0p, (void*)&wsp, (void*)&outp};
  hipLaunchCooperativeKernel(scan_kernel, dim3(64), dim3(256), kargs, 0, stream);
}